// Round 3
// baseline (236.822 us; speedup 1.0000x reference)
//
#include <hip/hip_runtime.h>
#include <stdint.h>

// Problem constants
#define B_SZ   8192
#define IN_DIM 320      // S + A
#define H_DIM  1024
#define E_NUM  8
#define OUT_DIM 257     // S + 1
#define TM     128
#define MAXT   (B_SZ / TM + E_NUM)   // 72 — worst-case M-tile count
#define W3ROWS 384                   // layer-3 N padded to 3 x 128

typedef __bf16 bf16x8 __attribute__((ext_vector_type(8)));
typedef float  f32x4  __attribute__((ext_vector_type(4)));

typedef unsigned int __attribute__((address_space(1))) as1_uint;
typedef unsigned int __attribute__((address_space(3))) as3_uint;

__device__ __forceinline__ void gload_lds16(const void* g, void* l) {
    // async global->LDS, 16B/lane; LDS dest is wave-uniform base + lane*16
    __builtin_amdgcn_global_load_lds((const as1_uint*)g, (as3_uint*)l, 16, 0, 0);
}

__device__ __forceinline__ unsigned short f2bf(float f) {
    unsigned int u = __float_as_uint(f);
    return (unsigned short)((u + 0x7fffu + ((u >> 16) & 1u)) >> 16);  // RNE
}

// ---------------------------------------------------------------------------
// Uber prep kernel: block 0 = bucket rows by expert + tile table; then
// x-concat/bf16-convert; then three transpose-converts (E,K,Nsrc) f32 ->
// (E,Ncols,K) bf16; then W3 reward-column extract into w3t row 256.
// w3t has 384 rows; rows 257..383 stay poison — discarded in gemm3 epilogue.
__global__ __launch_bounds__(256)
void k_prep(const float* __restrict__ state, const float* __restrict__ action,
            const int* __restrict__ idx,
            const float* __restrict__ W1, const float* __restrict__ W2,
            const float* __restrict__ W3,
            unsigned short* __restrict__ xb, unsigned short* __restrict__ w1t,
            unsigned short* __restrict__ w2t, unsigned short* __restrict__ w3t,
            int* __restrict__ order, int* __restrict__ te,
            int* __restrict__ tp0, int* __restrict__ tcnt) {
    __shared__ float tile[64][65];
    __shared__ int scnt[16][E_NUM];
    int bid = blockIdx.x, tid = threadIdx.x;

    if (bid == 0) {
        // ---- bucket ----
        int shard = tid & 15;
        if (tid < 128) ((int*)scnt)[tid] = 0;
        __syncthreads();
        for (int b = tid; b < B_SZ; b += 256) atomicAdd(&scnt[shard][idx[b]], 1);
        __syncthreads();
        if (tid == 0) {
            int pos = 0, tt = 0;
            for (int e = 0; e < E_NUM; e++) {
                int start = pos;
                for (int s = 0; s < 16; s++) { int c = scnt[s][e]; scnt[s][e] = pos; pos += c; }
                int tot = pos - start;
                for (int st = 0; st < tot; st += TM) {
                    te[tt] = e; tp0[tt] = start + st; tcnt[tt] = min(TM, tot - st); tt++;
                }
            }
            for (; tt < MAXT; tt++) { te[tt] = 0; tp0[tt] = 0; tcnt[tt] = 0; }
        }
        __syncthreads();
        for (int b = tid; b < B_SZ; b += 256) {
            int e = idx[b];
            int p = atomicAdd(&scnt[shard][e], 1);
            order[p] = b;
        }
        return;
    }

    if (bid <= 2560) {
        // ---- x = concat(state, action) -> bf16 ----  (2560 blocks, exact)
        int q = (bid - 1) * 256 + tid;   // quad id: b*80 + j
        int b = q / 80, j = q % 80;
        float4 v = (j < 64) ? ((const float4*)state)[b * 64 + j]
                            : ((const float4*)action)[b * 16 + (j - 64)];
        ushort4 o;
        o.x = f2bf(v.x); o.y = f2bf(v.y); o.z = f2bf(v.z); o.w = f2bf(v.w);
        ((ushort4*)xb)[q] = o;
        return;
    }

    if (bid < 5761) {
        // ---- transpose-convert: 64x64 tiles via LDS ----
        int e, kt, nt, K, Nsrc, dstRows;
        const float* src; unsigned short* dst;
        if (bid < 3201) {        // W1: (8,320,1024) -> (8,1024,320); 80 tiles/e
            int r = bid - 2561; e = r / 80; int m = r % 80; kt = m / 16; nt = m % 16;
            K = IN_DIM; Nsrc = H_DIM; dstRows = H_DIM; src = W1; dst = w1t;
        } else if (bid < 5249) { // W2: (8,1024,1024) -> (8,1024,1024); 256 tiles/e
            int r = bid - 3201; e = r / 256; int m = r % 256; kt = m / 16; nt = m % 16;
            K = H_DIM; Nsrc = H_DIM; dstRows = H_DIM; src = W2; dst = w2t;
        } else {                 // W3: (8,1024,257) -> rows 0..255 of (8,384,1024)
            int r = bid - 5249; e = r / 64; int m = r % 64; kt = m / 4; nt = m % 4;
            K = H_DIM; Nsrc = OUT_DIM; dstRows = W3ROWS; src = W3; dst = w3t;
        }
        int k0 = kt * 64, n0 = nt * 64;
        const float* s = src + (size_t)e * K * Nsrc;
        unsigned short* d = dst + (size_t)e * dstRows * K;
        int tx = tid & 63, ty = tid >> 6;
        for (int rr = ty; rr < 64; rr += 4)
            tile[rr][tx] = s[(size_t)(k0 + rr) * Nsrc + (n0 + tx)];
        __syncthreads();
        for (int rr = ty; rr < 64; rr += 4)
            d[(size_t)(n0 + rr) * K + (k0 + tx)] = f2bf(tile[tx][rr]);
        return;
    }

    // ---- W3 reward column -> w3t row 256 ----  (32 blocks)
    int i = (bid - 5761) * 256 + tid;        // 8192 = 8 experts x 1024 k
    int e = i >> 10, k = i & 1023;
    w3t[((size_t)e * W3ROWS + 256) * H_DIM + k] =
        f2bf(W3[((size_t)e * H_DIM + k) * OUT_DIM + 256]);
}

// ---------------------------------------------------------------------------
// Grouped GEMM, 128x128 tile, software-pipelined (2-stage LDS dbuf).
// 4 waves in 2x2; wave quadrant 64x64 = 4x4 frags of 16x16x32 bf16 MFMA.
// LDS XOR-swizzled: slot (row, chunk c) holds global 16B chunk c ^ ((row>>1)&3)
// so the 16-lane b128 fragment reads are 2-way (free).
// Wt: (E, wtRows, K) bf16, N-major (k contiguous).
// MODE 0: Hout[(p0+m)*1024 + n] = bf16(relu(acc + bias))
// MODE 1 (layer 3 + fused reward): n<256 -> Out[row*256+n] = state + acc + b;
//         n==256 -> Out[B*256 + row] = acc + b;  n>256 -> discard.
template <int K, bool GATHER, int MODE>
__global__ __launch_bounds__(256, 2)
void k_gemm(const unsigned short* __restrict__ Abase,
            const unsigned short* __restrict__ Wt, int wtRows,
            const float* __restrict__ bias, int bstride,
            unsigned short* __restrict__ Hout,
            float* __restrict__ Out, const float* __restrict__ state,
            const int* __restrict__ order,
            const int* __restrict__ te, const int* __restrict__ tp0,
            const int* __restrict__ tcnt) {
    constexpr int NI  = K / 32;
    constexpr int ABY = 128 * 64;         // A stage bytes (128 rows x 64B)
    constexpr int STG = 2 * ABY;          // A + B per stage = 16 KB
    __shared__ __align__(16) char lds[2 * STG];

    int t = blockIdx.x;
    int cnt = tcnt[t];
    if (cnt == 0) return;
    int e = te[t], p0 = tp0[t];
    int n0 = blockIdx.y * 128;
    int tid = threadIdx.x;
    int w = tid >> 6, lane = tid & 63;

    // staging: thread fills LDS slot (row=tid>>2, chunk=tid&3) in each 4 KB
    // half; fetches global chunk (tid&3) ^ swizzle(row). Rows r and r+64.
    int r  = tid >> 2;
    int cg = (tid & 3) ^ ((r >> 1) & 3);
    int rc0 = r < cnt ? r : cnt - 1;
    int rc1 = (r + 64) < cnt ? (r + 64) : cnt - 1;
    long ar0 = GATHER ? order[p0 + rc0] : (p0 + rc0);
    long ar1 = GATHER ? order[p0 + rc1] : (p0 + rc1);
    const unsigned short* aP0 = Abase + (size_t)ar0 * K + cg * 8;
    const unsigned short* aP1 = Abase + (size_t)ar1 * K + cg * 8;
    const unsigned short* bP0 = Wt + ((size_t)e * wtRows + n0 + r) * K + cg * 8;
    const unsigned short* bP1 = bP0 + (size_t)64 * K;

    auto stage = [&](int k0, int sb) {
        gload_lds16(aP0 + k0, lds + sb + tid * 16);
        gload_lds16(aP1 + k0, lds + sb + 4096 + tid * 16);
        gload_lds16(bP0 + k0, lds + sb + ABY + tid * 16);
        gload_lds16(bP1 + k0, lds + sb + ABY + 4096 + tid * 16);
    };

    f32x4 acc[4][4];
#pragma unroll
    for (int i = 0; i < 4; i++)
#pragma unroll
        for (int j = 0; j < 4; j++) acc[i][j] = (f32x4)0.f;

    const int m_off = (w >> 1) * 64, n_off = (w & 1) * 64;
    const int fm   = lane & 15;
    const int kc   = lane >> 4;
    const int koff = (kc ^ ((fm >> 1) & 3)) * 8;   // swizzled k-chunk (shorts)

    stage(0, 0);
    for (int it = 0; it < NI; ++it) {
        __syncthreads();                 // drains stage(it) loads (1 iter in flight)
        if (it + 1 < NI) stage((it + 1) * 32, ((it + 1) & 1) * STG);
        const unsigned short* As = (const unsigned short*)(lds + (it & 1) * STG);
        const unsigned short* Bs = As + ABY / 2;   // shorts

        bf16x8 af[4], bf[4];
#pragma unroll
        for (int i = 0; i < 4; i++)
            af[i] = *(const bf16x8*)&As[(m_off + i * 16 + fm) * 32 + koff];
#pragma unroll
        for (int j = 0; j < 4; j++)
            bf[j] = *(const bf16x8*)&Bs[(n_off + j * 16 + fm) * 32 + koff];
#pragma unroll
        for (int i = 0; i < 4; i++)
#pragma unroll
            for (int j = 0; j < 4; j++)
                acc[i][j] = __builtin_amdgcn_mfma_f32_16x16x32_bf16(
                    af[i], bf[j], acc[i][j], 0, 0, 0);
    }

    // epilogue: C/D mapping col = lane&15, row = (lane>>4)*4 + reg
    int col = lane & 15, rq = lane >> 4;
#pragma unroll
    for (int j = 0; j < 4; j++) {
        int n = n0 + n_off + j * 16 + col;
        float bv = (MODE == 0) ? bias[e * bstride + n]
                               : ((n <= 256) ? bias[e * bstride + n] : 0.f);
#pragma unroll
        for (int i = 0; i < 4; i++) {
#pragma unroll
            for (int rr = 0; rr < 4; rr++) {
                int m = m_off + i * 16 + rq * 4 + rr;
                if (m < cnt) {
                    float v = acc[i][j][rr] + bv;
                    if (MODE == 0) {
                        Hout[(size_t)(p0 + m) * H_DIM + n] = f2bf(fmaxf(v, 0.f));
                    } else {
                        int row = order[p0 + m];
                        if (n < 256) {
                            size_t o = (size_t)row * 256 + n;
                            Out[o] = state[o] + v;
                        } else if (n == 256) {
                            Out[(size_t)B_SZ * 256 + row] = v;   // reward
                        }
                    }
                }
            }
        }
    }
}

// ---------------------------------------------------------------------------
extern "C" void kernel_launch(void* const* d_in, const int* in_sizes, int n_in,
                              void* d_out, int out_size, void* d_ws, size_t ws_size,
                              hipStream_t stream) {
    const float* state  = (const float*)d_in[0];
    const float* action = (const float*)d_in[1];
    const int*   idx    = (const int*)d_in[2];
    const float* W1     = (const float*)d_in[3];
    const float* b1     = (const float*)d_in[4];
    const float* W2     = (const float*)d_in[5];
    const float* b2     = (const float*)d_in[6];
    const float* W3     = (const float*)d_in[7];
    const float* b3     = (const float*)d_in[8];
    float* out = (float*)d_out;

    char* ws = (char*)d_ws;
    size_t off = 0;
    auto alloc = [&](size_t bytes) -> void* {
        void* p = ws + off;
        off = (off + bytes + 255) & ~(size_t)255;
        return p;
    };
    unsigned short* xb  = (unsigned short*)alloc((size_t)B_SZ * IN_DIM * 2);
    unsigned short* w1t = (unsigned short*)alloc((size_t)E_NUM * H_DIM * IN_DIM * 2);
    unsigned short* w2t = (unsigned short*)alloc((size_t)E_NUM * H_DIM * H_DIM * 2);
    unsigned short* w3t = (unsigned short*)alloc((size_t)E_NUM * W3ROWS * H_DIM * 2);
    unsigned short* h1  = (unsigned short*)alloc((size_t)B_SZ * H_DIM * 2);
    unsigned short* h2  = (unsigned short*)alloc((size_t)B_SZ * H_DIM * 2);
    int* order = (int*)alloc(B_SZ * 4);
    int* te    = (int*)alloc(MAXT * 4);
    int* tp0   = (int*)alloc(MAXT * 4);
    int* tcnt  = (int*)alloc(MAXT * 4);

    // prep: bucket + convert x + transpose-convert W1/W2/W3 + reward column
    k_prep<<<5793, 256, 0, stream>>>(state, action, idx, W1, W2, W3,
                                     xb, w1t, w2t, w3t, order, te, tp0, tcnt);

    // layer 1: (B,320) x (320,1024) grouped, gather rows
    k_gemm<IN_DIM, true, 0><<<dim3(MAXT, 8), 256, 0, stream>>>(
        xb, w1t, H_DIM, b1, H_DIM, h1, nullptr, nullptr, order, te, tp0, tcnt);
    // layer 2: (B,1024) x (1024,1024)
    k_gemm<H_DIM, false, 0><<<dim3(MAXT, 8), 256, 0, stream>>>(
        h1, w2t, H_DIM, b2, H_DIM, h2, nullptr, nullptr, order, te, tp0, tcnt);
    // layer 3 + fused reward: (B,1024) x (1024, 384-padded)
    k_gemm<H_DIM, false, 1><<<dim3(MAXT, 3), 256, 0, stream>>>(
        h2, w3t, W3ROWS, b3, OUT_DIM, nullptr, out, state, order, te, tp0, tcnt);
}